// Round 1
// baseline (425.904 us; speedup 1.0000x reference)
//
#include <hip/hip_runtime.h>

#define NN 50000
#define TT 518
#define KC 32
#define LL 163
#define HH 128
#define EE 1600000
#define NB 196          // node blocks: 196*256 = 50176 >= NN

// deg[i] = sum of edge_attr over edges with col==i  (self-loop +1 added later)
__global__ __launch_bounds__(256) void k_deg(const int* __restrict__ col,
                                             const float* __restrict__ ea,
                                             float* __restrict__ deg) {
  int e = blockIdx.x * 256 + threadIdx.x;
  if (e < EE) atomicAdd(&deg[col[e]], ea[e]);
}

// dinv = rsqrt(deg+1); c init = dinv^2 (self-loop term)
__global__ __launch_bounds__(256) void k_dinv(const float* __restrict__ deg,
                                              float* __restrict__ dinv,
                                              float* __restrict__ c) {
  int i = blockIdx.x * 256 + threadIdx.x;
  if (i < NN) {
    float di = rsqrtf(deg[i] + 1.0f);
    dinv[i] = di;
    c[i] = di * di;
  }
}

// c[row] += dinv[row]*ea*dinv[col]   (mean-pool collapses scatter to scalar coef)
__global__ __launch_bounds__(256) void k_coef(const int* __restrict__ row,
                                              const int* __restrict__ col,
                                              const float* __restrict__ ea,
                                              const float* __restrict__ dinv,
                                              float* __restrict__ c) {
  int e = blockIdx.x * 256 + threadIdx.x;
  if (e < EE) {
    int r = row[e];
    atomicAdd(&c[r], dinv[r] * ea[e] * dinv[col[e]]);
  }
}

// v[l] += sum_n c[n] * relu(conv1d(x[:,n], w[n]) + b[n])[l]
// One thread per node column; 32-slot register ring (slot = t & 31).
// blockIdx -> (node block, l-chunk of 32). base_t = 96*lc is 0 mod 32.
__global__ __launch_bounds__(256) void k_conv(const float* __restrict__ x,
                                              const float* __restrict__ cw,
                                              const float* __restrict__ cb,
                                              const float* __restrict__ c,
                                              float* __restrict__ v) {
  __shared__ float vloc[32];
  int tid = threadIdx.x;
  if (tid < 32) vloc[tid] = 0.f;
  __syncthreads();

  int nb = blockIdx.x % NB;
  int lc = blockIdx.x / NB;      // 0..5
  int n = nb * 256 + tid;
  int nc = n < NN ? n : NN - 1;  // clamp for safe loads; cn=0 kills contribution
  float cn = n < NN ? c[n] : 0.f;
  float bn = cb[nc];

  float w[KC];
#pragma unroll
  for (int k = 0; k < KC; ++k) w[k] = cw[nc * KC + k];

  const float* xp = x + nc;
  int base_t = 96 * lc;
  float xwin[32];
#pragma unroll
  for (int k = 0; k < 32; ++k) xwin[k] = xp[(size_t)(base_t + k) * NN];

  int l0 = 32 * lc;
  int lane = tid & 63;

#pragma unroll
  for (int u = 0; u < 32; ++u) {
    if (l0 + u >= LL) break;     // uniform per block (lc==5 tail)
    // h_l = dot(xwin ring, w); 4 partial accumulators to break FMA dep chain
    float h0 = 0.f, h1 = 0.f, h2 = 0.f, h3 = 0.f;
#pragma unroll
    for (int k = 0; k < KC; k += 4) {
      h0 += xwin[(3 * u + k    ) & 31] * w[k];
      h1 += xwin[(3 * u + k + 1) & 31] * w[k + 1];
      h2 += xwin[(3 * u + k + 2) & 31] * w[k + 2];
      h3 += xwin[(3 * u + k + 3) & 31] * w[k + 3];
    }
    float hv = (h0 + h1) + (h2 + h3) + bn;
    hv = hv > 0.f ? hv : 0.f;
    float val = cn * hv;
#pragma unroll
    for (int off = 1; off < 64; off <<= 1) val += __shfl_xor(val, off, 64);
    if (lane == 0) atomicAdd(&vloc[u], val);
    // slide: bring in t = base_t + 3u + 32..34 (clamped loads only ever unused)
    int tn = base_t + 3 * u + 32;
    int t0c = tn     < TT ? tn     : TT - 1;
    int t1c = tn + 1 < TT ? tn + 1 : TT - 1;
    int t2c = tn + 2 < TT ? tn + 2 : TT - 1;
    xwin[(3 * u    ) & 31] = xp[(size_t)t0c * NN];
    xwin[(3 * u + 1) & 31] = xp[(size_t)t1c * NN];
    xwin[(3 * u + 2) & 31] = xp[(size_t)t2c * NN];
  }

  __syncthreads();
  if (tid < 32 && l0 + tid < LL) atomicAdd(&v[l0 + tid], vloc[tid]);
}

// out[h] = (sum_l v[l]*W[l][h]) / N + gcn_b[h]
__global__ __launch_bounds__(128) void k_out(const float* __restrict__ v,
                                             const float* __restrict__ W,
                                             const float* __restrict__ b,
                                             float* __restrict__ out) {
  int h = threadIdx.x;
  float s = 0.f;
  for (int l = 0; l < LL; ++l) s += v[l] * W[l * HH + h];
  out[h] = s * (1.0f / NN) + b[h];
}

extern "C" void kernel_launch(void* const* d_in, const int* in_sizes, int n_in,
                              void* d_out, int out_size, void* d_ws, size_t ws_size,
                              hipStream_t stream) {
  const float* x  = (const float*)d_in[0];
  const int*   ei = (const int*)d_in[1];
  const float* ea = (const float*)d_in[2];
  const float* cw = (const float*)d_in[3];
  const float* cb = (const float*)d_in[4];
  const float* gW = (const float*)d_in[5];
  const float* gb = (const float*)d_in[6];
  float* out = (float*)d_out;

  float* ws   = (float*)d_ws;
  float* deg  = ws;                 // N floats
  float* v    = ws + NN;            // 256 floats (163 used)
  float* dinv = ws + NN + 256;      // N floats
  float* c    = ws + 2 * NN + 256;  // N floats

  const int* row = ei;
  const int* col = ei + EE;

  // zero deg and v in one contiguous memset (ws is poisoned each call)
  hipMemsetAsync(deg, 0, (NN + 256) * sizeof(float), stream);

  k_deg <<<(EE + 255) / 256, 256, 0, stream>>>(col, ea, deg);
  k_dinv<<<(NN + 255) / 256, 256, 0, stream>>>(deg, dinv, c);
  k_coef<<<(EE + 255) / 256, 256, 0, stream>>>(row, col, ea, dinv, c);
  k_conv<<<NB * 6, 256, 0, stream>>>(x, cw, cb, c, v);
  k_out <<<1, 128, 0, stream>>>(v, gW, gb, out);
}